// Round 3
// baseline (733.892 us; speedup 1.0000x reference)
//
#include <hip/hip_runtime.h>
#include <hip/hip_bf16.h>
#include <math.h>

#define DI __device__ __forceinline__

static constexpr float SCALE = 0.17677669529663687f;  // 1/sqrt(32)

// ----------------------------- device scratch ------------------------------
// All intermediates f32 in module globals (zero dependence on d_ws / ws_size).
__device__ int   g_isf32;                               // 0 = bf16 inputs, 1 = f32 inputs
__device__ float g_q[(size_t)64 * 4096 * 32];           // q, [bh][n][32], pre-scaled
__device__ float g_conv[(size_t)2048 * 256];            // conv out, [b*nk][C]
__device__ float g_ln[(size_t)2048 * 256];              // LN out
__device__ float g_k[(size_t)64 * 256 * 32];            // K, [bh][nk][32]
__device__ float g_v[(size_t)64 * 256 * 32];            // V
__device__ float g_attn[(size_t)32768 * 256];           // attn out, [b*n][C]
__device__ float g_wt[(size_t)4096 * 256];              // conv weight, [k=tap*256+ci][o]

DI float bfbits2f(unsigned short b) { return __uint_as_float(((unsigned)b) << 16); }

DI unsigned short f2bf(float f) {
  unsigned u = __float_as_uint(f);
  unsigned r = (u + 0x7fffu + ((u >> 16) & 1u)) >> 16;
  return (unsigned short)r;
}

DI float4 ld_bf4(const unsigned short* p) {
  ushort4 u = *(const ushort4*)p;
  return make_float4(bfbits2f(u.x), bfbits2f(u.y), bfbits2f(u.z), bfbits2f(u.w));
}

DI float ld1(const void* p, size_t i, int f32) {
  return f32 ? ((const float*)p)[i] : bfbits2f(((const unsigned short*)p)[i]);
}

DI float4 ld4(const void* p, size_t i, int f32) {
  if (f32) return *(const float4*)((const float*)p + i);
  return ld_bf4((const unsigned short*)p + i);
}

// ---------------------------------------------------------------------------
// Input dtype detection: decode first 16384 ushorts of x as bf16. True bf16
// N(0,1) data -> max ~5. fp32 data read as bf16 -> huge/NaN decodes, certain.
// ---------------------------------------------------------------------------
__global__ void k_detect(const void* __restrict__ xp) {
  __shared__ float red[256];
  int t = threadIdx.x;
  const unsigned short* p = (const unsigned short*)xp;
  float m = 0.f;
  for (int i = t; i < 16384; i += 256) {
    float v = fabsf(bfbits2f(p[i]));
    m = (v == v && v < 1e30f) ? fmaxf(m, v) : 1e30f;
  }
  red[t] = m;
  __syncthreads();
  for (int s = 128; s > 0; s >>= 1) {
    if (t < s) red[t] = fmaxf(red[t], red[t + s]);
    __syncthreads();
  }
  if (t == 0) g_isf32 = (red[0] > 1e4f) ? 1 : 0;
}

// ---------------------------------------------------------------------------
// sr_w transpose: OIHW [256,256,4,4] -> g_wt[k=tap*256+ci][o]  (f32)
// ---------------------------------------------------------------------------
__global__ void k_wt(const void* __restrict__ srw) {
  int f32 = g_isf32;
  int e = blockIdx.x * 256 + threadIdx.x;   // over 4096*256
  int kidx = e >> 8, o = e & 255;
  int ci = kidx & 255, tap = kidx >> 8;     // tap = kh*4+kw
  g_wt[e] = ld1(srw, (size_t)o * 4096 + ci * 16 + tap, f32);
}

// ---------------------------------------------------------------------------
// Shared tiled GEMM, 64x64 tile, BK=16, 256 threads, 4x4 per thread, fp32 acc.
// MODE 0: q-proj   A=x [32768,256] (in)    B=q_w (in)        -> g_q (*SCALE, permuted)
// MODE 1: conv     A=x gather (in)         B=g_wt f32        -> g_conv (+sr_b)
// MODE 2: kv       A=g_ln f32 [2048,256]   B=kv_w (in)       -> g_k / g_v (permuted)
// MODE 3: proj     A=g_attn f32 [32768,256] B=proj_w (in)    -> out (+proj_b, out dtype)
// ---------------------------------------------------------------------------
template <int MODE>
__launch_bounds__(256, 2)
__global__ void k_gemm(const void* __restrict__ Ax,
                       const void* __restrict__ Bp,
                       const void* __restrict__ biasp,
                       void* __restrict__ outp) {
  constexpr int K   = (MODE == 1) ? 4096 : 256;
  constexpr int LDB = (MODE == 2) ? 512 : 256;
  const int f32 = g_isf32;

  __shared__ float As[16][64];
  __shared__ float Bs[16][64];

  const int tid = threadIdx.x;
  const int tx = tid & 15, ty = tid >> 4;
  const int m0 = blockIdx.x * 64, n0 = blockIdx.y * 64;

  const int arow = tid >> 2;         // 0..63
  const int akk  = (tid & 3) * 4;    // 0,4,8,12
  const int bkk  = tid >> 4;         // 0..15
  const int bcc  = (tid & 15) * 4;   // 0..60

  float acc[4][4] = {};

  for (int k0 = 0; k0 < K; k0 += 16) {
    float4 av;
    if constexpr (MODE == 1) {
      int m = m0 + arow;
      int bb = m >> 8, sp = m & 255;
      int oh = sp >> 4, ow = sp & 15;
      int tap = k0 >> 8;                    // constant within 16-wide k-tile
      int kh = tap >> 2, kw = tap & 3;
      int n = (4 * oh + kh) * 64 + 4 * ow + kw;
      int ci = (k0 & 255) + akk;
      av = ld4(Ax, ((size_t)(bb * 4096 + n) * 256) + ci, f32);
    } else if constexpr (MODE == 0) {
      av = ld4(Ax, (size_t)(m0 + arow) * 256 + k0 + akk, f32);
    } else {
      const float* A = (MODE == 2) ? g_ln : g_attn;
      av = *(const float4*)&A[(size_t)(m0 + arow) * 256 + k0 + akk];
    }
    As[akk + 0][arow] = av.x;
    As[akk + 1][arow] = av.y;
    As[akk + 2][arow] = av.z;
    As[akk + 3][arow] = av.w;

    float4 bv;
    if constexpr (MODE == 1)
      bv = *(const float4*)&g_wt[(size_t)(k0 + bkk) * 256 + n0 + bcc];
    else
      bv = ld4(Bp, (size_t)(k0 + bkk) * LDB + n0 + bcc, f32);
    *(float4*)&Bs[bkk][bcc] = bv;

    __syncthreads();
#pragma unroll
    for (int k = 0; k < 16; ++k) {
      float4 a = *(const float4*)&As[k][ty * 4];
      float4 b = *(const float4*)&Bs[k][tx * 4];
      float va[4] = {a.x, a.y, a.z, a.w};
      float vb[4] = {b.x, b.y, b.z, b.w};
#pragma unroll
      for (int i = 0; i < 4; ++i)
#pragma unroll
        for (int j = 0; j < 4; ++j)
          acc[i][j] = fmaf(va[i], vb[j], acc[i][j]);
    }
    __syncthreads();
  }

#pragma unroll
  for (int i = 0; i < 4; ++i) {
    int m = m0 + ty * 4 + i;
#pragma unroll
    for (int j = 0; j < 4; ++j) {
      int c = n0 + tx * 4 + j;
      float v = acc[i][j];
      if constexpr (MODE == 0) {
        int b = m >> 12, n = m & 4095;
        int h = c >> 5, d = c & 31;
        g_q[(((size_t)(b * 8 + h) * 4096 + n) << 5) + d] = v * SCALE;
      } else if constexpr (MODE == 1) {
        g_conv[(size_t)m * 256 + c] = v + ld1(biasp, c, f32);
      } else if constexpr (MODE == 2) {
        int s = c >> 8, h = (c >> 5) & 7, d = c & 31;
        int bb = m >> 8, nk = m & 255;
        float* dst = s ? g_v : g_k;
        dst[(((size_t)(bb * 8 + h) * 256 + nk) << 5) + d] = v;
      } else {
        float r = v + ld1(biasp, c, f32);
        if (f32) ((float*)outp)[(size_t)m * 256 + c] = r;
        else     ((unsigned short*)outp)[(size_t)m * 256 + c] = f2bf(r);
      }
    }
  }
}

// ---------------------------------------------------------------------------
// LayerNorm over C=256 of g_conv [2048, 256] -> g_ln (f32)
// ---------------------------------------------------------------------------
__global__ void k_ln(const void* __restrict__ lw, const void* __restrict__ lb) {
  const int f32 = g_isf32;
  int row = blockIdx.x;
  int t = threadIdx.x;
  float v = g_conv[(size_t)row * 256 + t];
  float s = v, sq = v * v;
#pragma unroll
  for (int off = 32; off >= 1; off >>= 1) {
    s += __shfl_down(s, off, 64);
    sq += __shfl_down(sq, off, 64);
  }
  __shared__ float rs[4], rq[4];
  int wid = t >> 6;
  if ((t & 63) == 0) { rs[wid] = s; rq[wid] = sq; }
  __syncthreads();
  float st = rs[0] + rs[1] + rs[2] + rs[3];
  float qt = rq[0] + rq[1] + rq[2] + rq[3];
  float mu = st * (1.0f / 256.0f);
  float var = qt * (1.0f / 256.0f) - mu * mu;
  float r = rsqrtf(var + 1e-5f);
  g_ln[(size_t)row * 256 + t] = (v - mu) * r * ld1(lw, t, f32) + ld1(lb, t, f32);
}

// ---------------------------------------------------------------------------
// Attention: grid (16 qtiles, 64 bh). One thread per q row, K/V in LDS (f32),
// online softmax. q pre-scaled. Output f32 to g_attn [B, N, C].
// ---------------------------------------------------------------------------
__launch_bounds__(256, 2)
__global__ void k_attn() {
  __shared__ float kls[256 * 32];
  __shared__ float vls[256 * 32];
  int bh = blockIdx.y;
  int tid = threadIdx.x;
  const float4* k4 = (const float4*)(g_k + (size_t)bh * (256 * 32));
  const float4* v4 = (const float4*)(g_v + (size_t)bh * (256 * 32));
  float4* kl4 = (float4*)kls;
  float4* vl4 = (float4*)vls;
  for (int e = tid; e < 2048; e += 256) { kl4[e] = k4[e]; vl4[e] = v4[e]; }
  __syncthreads();

  int n = blockIdx.x * 256 + tid;
  const float* qp = g_q + ((size_t)bh * 4096 + n) * 32;
  float qr[32];
#pragma unroll
  for (int i = 0; i < 8; ++i) {
    float4 f = *(const float4*)(qp + i * 4);
    qr[i * 4 + 0] = f.x; qr[i * 4 + 1] = f.y;
    qr[i * 4 + 2] = f.z; qr[i * 4 + 3] = f.w;
  }

  float mx = -1e30f, l = 0.f;
  float o[32] = {};
  for (int j = 0; j < 256; ++j) {
    const float* kj = kls + j * 32;
    float s = 0.f;
#pragma unroll
    for (int i = 0; i < 8; ++i) {
      float4 f = *(const float4*)(kj + i * 4);
      s = fmaf(qr[i * 4 + 0], f.x, s);
      s = fmaf(qr[i * 4 + 1], f.y, s);
      s = fmaf(qr[i * 4 + 2], f.z, s);
      s = fmaf(qr[i * 4 + 3], f.w, s);
    }
    float mn = fmaxf(mx, s);
    float al = __expf(mx - mn);
    float p = __expf(s - mn);
    l = l * al + p;
    const float* vj = vls + j * 32;
#pragma unroll
    for (int i = 0; i < 8; ++i) {
      float4 f = *(const float4*)(vj + i * 4);
      o[i * 4 + 0] = o[i * 4 + 0] * al + p * f.x;
      o[i * 4 + 1] = o[i * 4 + 1] * al + p * f.y;
      o[i * 4 + 2] = o[i * 4 + 2] * al + p * f.z;
      o[i * 4 + 3] = o[i * 4 + 3] * al + p * f.w;
    }
    mx = mn;
  }
  float inv = 1.0f / l;
  int b = bh >> 3, h = bh & 7;
  float* op = g_attn + ((size_t)(b * 4096 + n) * 256) + h * 32;
#pragma unroll
  for (int i = 0; i < 8; ++i)
    ((float4*)op)[i] = make_float4(o[i * 4] * inv, o[i * 4 + 1] * inv,
                                   o[i * 4 + 2] * inv, o[i * 4 + 3] * inv);
}

// ---------------------------------------------------------------------------
extern "C" void kernel_launch(void* const* d_in, const int* in_sizes, int n_in,
                              void* d_out, int out_size, void* d_ws, size_t ws_size,
                              hipStream_t stream) {
  const void* x   = d_in[0];
  // d_in[1], d_in[2] are H, W (int) — fixed at 64.
  const void* qw  = d_in[3];
  const void* kvw = d_in[4];
  const void* srw = d_in[5];
  const void* srb = d_in[6];
  const void* lnw = d_in[7];
  const void* lnb = d_in[8];
  const void* pw  = d_in[9];
  const void* pb  = d_in[10];

  // 0. input dtype detection (bf16 vs f32)
  k_detect<<<1, 256, 0, stream>>>(x);
  // 1. transpose sr_w
  k_wt<<<4096, 256, 0, stream>>>(srw);
  // 2. q projection (scaled, permuted to [bh, n, 32])
  k_gemm<0><<<dim3(512, 4), 256, 0, stream>>>(x, qw, nullptr, nullptr);
  // 3. spatial-reduction conv as GEMM
  k_gemm<1><<<dim3(32, 4), 256, 0, stream>>>(x, nullptr, srb, nullptr);
  // 4. layernorm
  k_ln<<<2048, 256, 0, stream>>>(lnw, lnb);
  // 5. kv projection (split to g_k / g_v, [bh, nk, 32])
  k_gemm<2><<<dim3(32, 8), 256, 0, stream>>>(nullptr, kvw, nullptr, nullptr);
  // 6. attention
  k_attn<<<dim3(16, 64), 256, 0, stream>>>();
  // 7. output projection + bias -> out (dtype-matched)
  k_gemm<3><<<dim3(512, 4), 256, 0, stream>>>(nullptr, pw, pb, d_out);
}

// Round 4
// 563.879 us; speedup vs baseline: 1.3015x; 1.3015x over previous
//
#include <hip/hip_runtime.h>
#include <hip/hip_bf16.h>
#include <math.h>

#define DI __device__ __forceinline__

static constexpr float SCALE = 0.17677669529663687f;  // 1/sqrt(32)

// ----------------------------- device scratch ------------------------------
// All intermediates f32 in module globals (zero dependence on d_ws / ws_size).
__device__ int   g_isf32;                               // 0 = bf16 inputs, 1 = f32 inputs
__device__ float g_q[(size_t)64 * 4096 * 32];           // q, [bh][n][32], pre-scaled
__device__ float g_convp[(size_t)16 * 2048 * 256];      // conv split-K partials
__device__ float g_conv[(size_t)2048 * 256];            // conv out, [b*nk][C]
__device__ float g_ln[(size_t)2048 * 256];              // LN out
__device__ float g_k[(size_t)64 * 256 * 32];            // K, [bh][nk][32]
__device__ float g_v[(size_t)64 * 256 * 32];            // V
__device__ float g_attn[(size_t)32768 * 256];           // attn out, [b*n][C]
__device__ float g_wt[(size_t)4096 * 256];              // conv weight, [k=tap*256+ci][o]

DI float bfbits2f(unsigned short b) { return __uint_as_float(((unsigned)b) << 16); }

DI unsigned short f2bf(float f) {
  unsigned u = __float_as_uint(f);
  unsigned r = (u + 0x7fffu + ((u >> 16) & 1u)) >> 16;
  return (unsigned short)r;
}

DI float4 ld_bf4(const unsigned short* p) {
  ushort4 u = *(const ushort4*)p;
  return make_float4(bfbits2f(u.x), bfbits2f(u.y), bfbits2f(u.z), bfbits2f(u.w));
}

DI float ld1(const void* p, size_t i, int f32) {
  return f32 ? ((const float*)p)[i] : bfbits2f(((const unsigned short*)p)[i]);
}

DI float4 ld4(const void* p, size_t i, int f32) {
  if (f32) return *(const float4*)((const float*)p + i);
  return ld_bf4((const unsigned short*)p + i);
}

// ---------------------------------------------------------------------------
// Input dtype detection: decode first 16384 ushorts of x as bf16. True bf16
// N(0,1) data -> max ~5. fp32 data read as bf16 -> huge/NaN decodes, certain.
// ---------------------------------------------------------------------------
__global__ void k_detect(const void* __restrict__ xp) {
  __shared__ float red[256];
  int t = threadIdx.x;
  const unsigned short* p = (const unsigned short*)xp;
  float m = 0.f;
  for (int i = t; i < 16384; i += 256) {
    float v = fabsf(bfbits2f(p[i]));
    m = (v == v && v < 1e30f) ? fmaxf(m, v) : 1e30f;
  }
  red[t] = m;
  __syncthreads();
  for (int s = 128; s > 0; s >>= 1) {
    if (t < s) red[t] = fmaxf(red[t], red[t + s]);
    __syncthreads();
  }
  if (t == 0) g_isf32 = (red[0] > 1e4f) ? 1 : 0;
}

// ---------------------------------------------------------------------------
// sr_w transpose: OIHW [256,256,4,4] -> g_wt[k=tap*256+ci][o]  (f32)
// ---------------------------------------------------------------------------
__global__ void k_wt(const void* __restrict__ srw) {
  int f32 = g_isf32;
  int e = blockIdx.x * 256 + threadIdx.x;   // over 4096*256
  int kidx = e >> 8, o = e & 255;
  int ci = kidx & 255, tap = kidx >> 8;     // tap = kh*4+kw
  g_wt[e] = ld1(srw, (size_t)o * 4096 + ci * 16 + tap, f32);
}

// ---------------------------------------------------------------------------
// Shared tiled GEMM, 64x64 tile, BK=16, 256 threads, 4x4 per thread, fp32 acc.
// MODE 0: q-proj   A=x [32768,256] (in)     B=q_w (in)     -> g_q (*SCALE, permuted)
// MODE 1: conv     A=x gather (in), split-K B=g_wt f32     -> g_convp[z] (partial)
// MODE 2: kv       A=g_ln f32 [2048,256]    B=kv_w (in)    -> g_k / g_v (permuted)
// MODE 3: proj     A=g_attn f32 [32768,256] B=proj_w (in)  -> out (+proj_b, out dtype)
// ---------------------------------------------------------------------------
template <int MODE>
__launch_bounds__(256, 2)
__global__ void k_gemm(const void* __restrict__ Ax,
                       const void* __restrict__ Bp,
                       const void* __restrict__ biasp,
                       void* __restrict__ outp) {
  constexpr int LDB = (MODE == 2) ? 512 : 256;
  const int f32 = g_isf32;

  __shared__ float As[16][64];
  __shared__ float Bs[16][64];

  const int tid = threadIdx.x;
  const int tx = tid & 15, ty = tid >> 4;
  const int m0 = blockIdx.x * 64, n0 = blockIdx.y * 64;
  const int kbeg = (MODE == 1) ? blockIdx.z * 256 : 0;

  const int arow = tid >> 2;         // 0..63
  const int akk  = (tid & 3) * 4;    // 0,4,8,12
  const int bkk  = tid >> 4;         // 0..15
  const int bcc  = (tid & 15) * 4;   // 0..60

  float acc[4][4] = {};

  for (int k0 = kbeg; k0 < kbeg + 256; k0 += 16) {
    float4 av;
    if constexpr (MODE == 1) {
      int m = m0 + arow;
      int bb = m >> 8, sp = m & 255;
      int oh = sp >> 4, ow = sp & 15;
      int tap = k0 >> 8;                    // == blockIdx.z (one tap per chunk)
      int kh = tap >> 2, kw = tap & 3;
      int n = (4 * oh + kh) * 64 + 4 * ow + kw;
      int ci = (k0 & 255) + akk;
      av = ld4(Ax, ((size_t)(bb * 4096 + n) * 256) + ci, f32);
    } else if constexpr (MODE == 0) {
      av = ld4(Ax, (size_t)(m0 + arow) * 256 + k0 + akk, f32);
    } else {
      const float* A = (MODE == 2) ? g_ln : g_attn;
      av = *(const float4*)&A[(size_t)(m0 + arow) * 256 + k0 + akk];
    }
    As[akk + 0][arow] = av.x;
    As[akk + 1][arow] = av.y;
    As[akk + 2][arow] = av.z;
    As[akk + 3][arow] = av.w;

    float4 bv;
    if constexpr (MODE == 1)
      bv = *(const float4*)&g_wt[(size_t)(k0 + bkk) * 256 + n0 + bcc];
    else
      bv = ld4(Bp, (size_t)((k0 - kbeg) + bkk) * LDB + n0 + bcc, f32);
    *(float4*)&Bs[bkk][bcc] = bv;

    __syncthreads();
#pragma unroll
    for (int k = 0; k < 16; ++k) {
      float4 a = *(const float4*)&As[k][ty * 4];
      float4 b = *(const float4*)&Bs[k][tx * 4];
      float va[4] = {a.x, a.y, a.z, a.w};
      float vb[4] = {b.x, b.y, b.z, b.w};
#pragma unroll
      for (int i = 0; i < 4; ++i)
#pragma unroll
        for (int j = 0; j < 4; ++j)
          acc[i][j] = fmaf(va[i], vb[j], acc[i][j]);
    }
    __syncthreads();
  }

#pragma unroll
  for (int i = 0; i < 4; ++i) {
    int m = m0 + ty * 4 + i;
#pragma unroll
    for (int j = 0; j < 4; ++j) {
      int c = n0 + tx * 4 + j;
      float v = acc[i][j];
      if constexpr (MODE == 0) {
        int b = m >> 12, n = m & 4095;
        int h = c >> 5, d = c & 31;
        g_q[(((size_t)(b * 8 + h) * 4096 + n) << 5) + d] = v * SCALE;
      } else if constexpr (MODE == 1) {
        g_convp[((size_t)blockIdx.z * 2048 + m) * 256 + c] = v;
      } else if constexpr (MODE == 2) {
        int s = c >> 8, h = (c >> 5) & 7, d = c & 31;
        int bb = m >> 8, nk = m & 255;
        float* dst = s ? g_v : g_k;
        dst[(((size_t)(bb * 8 + h) * 256 + nk) << 5) + d] = v;
      } else {
        float r = v + ld1(biasp, c, f32);
        if (f32) ((float*)outp)[(size_t)m * 256 + c] = r;
        else     ((unsigned short*)outp)[(size_t)m * 256 + c] = f2bf(r);
      }
    }
  }
}

// ---------------------------------------------------------------------------
// Reduce split-K conv partials + bias -> g_conv.  grid 2048, block 256.
// ---------------------------------------------------------------------------
__global__ void k_red(const void* __restrict__ biasp) {
  const int f32 = g_isf32;
  int row = blockIdx.x, c = threadIdx.x;
  size_t idx = (size_t)row * 256 + c;
  float s = 0.f;
#pragma unroll
  for (int z = 0; z < 16; ++z) s += g_convp[(size_t)z * (2048 * 256) + idx];
  g_conv[idx] = s + ld1(biasp, c, f32);
}

// ---------------------------------------------------------------------------
// LayerNorm over C=256 of g_conv [2048, 256] -> g_ln (f32)
// ---------------------------------------------------------------------------
__global__ void k_ln(const void* __restrict__ lw, const void* __restrict__ lb) {
  const int f32 = g_isf32;
  int row = blockIdx.x;
  int t = threadIdx.x;
  float v = g_conv[(size_t)row * 256 + t];
  float s = v, sq = v * v;
#pragma unroll
  for (int off = 32; off >= 1; off >>= 1) {
    s += __shfl_down(s, off, 64);
    sq += __shfl_down(sq, off, 64);
  }
  __shared__ float rs[4], rq[4];
  int wid = t >> 6;
  if ((t & 63) == 0) { rs[wid] = s; rq[wid] = sq; }
  __syncthreads();
  float st = rs[0] + rs[1] + rs[2] + rs[3];
  float qt = rq[0] + rq[1] + rq[2] + rq[3];
  float mu = st * (1.0f / 256.0f);
  float var = qt * (1.0f / 256.0f) - mu * mu;
  float r = rsqrtf(var + 1e-5f);
  g_ln[(size_t)row * 256 + t] = (v - mu) * r * ld1(lw, t, f32) + ld1(lb, t, f32);
}

// ---------------------------------------------------------------------------
// Attention: grid (16 qtiles, 64 bh). One thread per q row, K/V in LDS (f32),
// online softmax. q pre-scaled. Output f32 to g_attn [B, N, C].
// ---------------------------------------------------------------------------
__launch_bounds__(256, 2)
__global__ void k_attn() {
  __shared__ float kls[256 * 32];
  __shared__ float vls[256 * 32];
  int bh = blockIdx.y;
  int tid = threadIdx.x;
  const float4* k4 = (const float4*)(g_k + (size_t)bh * (256 * 32));
  const float4* v4 = (const float4*)(g_v + (size_t)bh * (256 * 32));
  float4* kl4 = (float4*)kls;
  float4* vl4 = (float4*)vls;
  for (int e = tid; e < 2048; e += 256) { kl4[e] = k4[e]; vl4[e] = v4[e]; }
  __syncthreads();

  int n = blockIdx.x * 256 + tid;
  const float* qp = g_q + ((size_t)bh * 4096 + n) * 32;
  float qr[32];
#pragma unroll
  for (int i = 0; i < 8; ++i) {
    float4 f = *(const float4*)(qp + i * 4);
    qr[i * 4 + 0] = f.x; qr[i * 4 + 1] = f.y;
    qr[i * 4 + 2] = f.z; qr[i * 4 + 3] = f.w;
  }

  float mx = -1e30f, l = 0.f;
  float o[32] = {};
  for (int j = 0; j < 256; ++j) {
    const float* kj = kls + j * 32;
    float s = 0.f;
#pragma unroll
    for (int i = 0; i < 8; ++i) {
      float4 f = *(const float4*)(kj + i * 4);
      s = fmaf(qr[i * 4 + 0], f.x, s);
      s = fmaf(qr[i * 4 + 1], f.y, s);
      s = fmaf(qr[i * 4 + 2], f.z, s);
      s = fmaf(qr[i * 4 + 3], f.w, s);
    }
    float mn = fmaxf(mx, s);
    float al = __expf(mx - mn);
    float p = __expf(s - mn);
    l = l * al + p;
    const float* vj = vls + j * 32;
#pragma unroll
    for (int i = 0; i < 8; ++i) {
      float4 f = *(const float4*)(vj + i * 4);
      o[i * 4 + 0] = o[i * 4 + 0] * al + p * f.x;
      o[i * 4 + 1] = o[i * 4 + 1] * al + p * f.y;
      o[i * 4 + 2] = o[i * 4 + 2] * al + p * f.z;
      o[i * 4 + 3] = o[i * 4 + 3] * al + p * f.w;
    }
    mx = mn;
  }
  float inv = 1.0f / l;
  int b = bh >> 3, h = bh & 7;
  float* op = g_attn + ((size_t)(b * 4096 + n) * 256) + h * 32;
#pragma unroll
  for (int i = 0; i < 8; ++i)
    ((float4*)op)[i] = make_float4(o[i * 4] * inv, o[i * 4 + 1] * inv,
                                   o[i * 4 + 2] * inv, o[i * 4 + 3] * inv);
}

// ---------------------------------------------------------------------------
extern "C" void kernel_launch(void* const* d_in, const int* in_sizes, int n_in,
                              void* d_out, int out_size, void* d_ws, size_t ws_size,
                              hipStream_t stream) {
  const void* x   = d_in[0];
  // d_in[1], d_in[2] are H, W (int) — fixed at 64.
  const void* qw  = d_in[3];
  const void* kvw = d_in[4];
  const void* srw = d_in[5];
  const void* srb = d_in[6];
  const void* lnw = d_in[7];
  const void* lnb = d_in[8];
  const void* pw  = d_in[9];
  const void* pb  = d_in[10];

  // 0. input dtype detection (bf16 vs f32)
  k_detect<<<1, 256, 0, stream>>>(x);
  // 1. transpose sr_w
  k_wt<<<4096, 256, 0, stream>>>(srw);
  // 2. q projection (scaled, permuted to [bh, n, 32])
  k_gemm<0><<<dim3(512, 4), 256, 0, stream>>>(x, qw, nullptr, nullptr);
  // 3. spatial-reduction conv as GEMM, split-K 16 (one tap per z)
  k_gemm<1><<<dim3(32, 4, 16), 256, 0, stream>>>(x, nullptr, nullptr, nullptr);
  // 3b. reduce partials + bias
  k_red<<<2048, 256, 0, stream>>>(srb);
  // 4. layernorm
  k_ln<<<2048, 256, 0, stream>>>(lnw, lnb);
  // 5. kv projection (split to g_k / g_v, [bh, nk, 32])
  k_gemm<2><<<dim3(32, 8), 256, 0, stream>>>(nullptr, kvw, nullptr, nullptr);
  // 6. attention
  k_attn<<<dim3(16, 64), 256, 0, stream>>>();
  // 7. output projection + bias -> out (dtype-matched)
  k_gemm<3><<<dim3(512, 4), 256, 0, stream>>>(nullptr, pw, pb, d_out);
}

// Round 5
// 423.107 us; speedup vs baseline: 1.7345x; 1.3327x over previous
//
#include <hip/hip_runtime.h>
#include <hip/hip_bf16.h>
#include <math.h>

#define DI __device__ __forceinline__

static constexpr float SCALE = 0.17677669529663687f;  // 1/sqrt(32)

typedef short bf16x8 __attribute__((ext_vector_type(8)));
typedef float f32x4 __attribute__((ext_vector_type(4)));

// ----------------------------- device scratch ------------------------------
__device__ int   g_isf32;                               // 0 = bf16 inputs, 1 = f32 inputs
__device__ unsigned short g_qh[(size_t)64 * 4096 * 32]; // q hi bf16, [bh][n][32], pre-scaled
__device__ unsigned short g_ql[(size_t)64 * 4096 * 32]; // q lo bf16
__device__ unsigned short g_kh[(size_t)64 * 256 * 32];  // K hi bf16, [bh][key][32]
__device__ unsigned short g_kl[(size_t)64 * 256 * 32];  // K lo
__device__ unsigned short g_vth[(size_t)64 * 32 * 256]; // V hi bf16 transposed, [bh][d][key]
__device__ unsigned short g_vtl[(size_t)64 * 32 * 256]; // V lo
__device__ float g_convp[(size_t)16 * 2048 * 256];      // conv split-K partials
__device__ float g_conv[(size_t)2048 * 256];            // conv out
__device__ float g_ln[(size_t)2048 * 256];              // LN out
__device__ float g_attn[(size_t)32768 * 256];           // attn out f32, [b*n][C]
__device__ float g_wt[(size_t)4096 * 256];              // conv weight, [k=tap*256+ci][o]

DI float bfbits2f(unsigned short b) { return __uint_as_float(((unsigned)b) << 16); }

DI unsigned short f2bf(float f) {
  unsigned u = __float_as_uint(f);
  unsigned r = (u + 0x7fffu + ((u >> 16) & 1u)) >> 16;
  return (unsigned short)r;
}

DI float4 ld_bf4(const unsigned short* p) {
  ushort4 u = *(const ushort4*)p;
  return make_float4(bfbits2f(u.x), bfbits2f(u.y), bfbits2f(u.z), bfbits2f(u.w));
}

DI float ld1(const void* p, size_t i, int f32) {
  return f32 ? ((const float*)p)[i] : bfbits2f(((const unsigned short*)p)[i]);
}

DI float4 ld4(const void* p, size_t i, int f32) {
  if (f32) return *(const float4*)((const float*)p + i);
  return ld_bf4((const unsigned short*)p + i);
}

// ---------------------------------------------------------------------------
__global__ void k_detect(const void* __restrict__ xp) {
  __shared__ float red[256];
  int t = threadIdx.x;
  const unsigned short* p = (const unsigned short*)xp;
  float m = 0.f;
  for (int i = t; i < 16384; i += 256) {
    float v = fabsf(bfbits2f(p[i]));
    m = (v == v && v < 1e30f) ? fmaxf(m, v) : 1e30f;
  }
  red[t] = m;
  __syncthreads();
  for (int s = 128; s > 0; s >>= 1) {
    if (t < s) red[t] = fmaxf(red[t], red[t + s]);
    __syncthreads();
  }
  if (t == 0) g_isf32 = (red[0] > 1e4f) ? 1 : 0;
}

// ---------------------------------------------------------------------------
__global__ void k_wt(const void* __restrict__ srw) {
  int f32 = g_isf32;
  int e = blockIdx.x * 256 + threadIdx.x;
  int kidx = e >> 8, o = e & 255;
  int ci = kidx & 255, tap = kidx >> 8;
  g_wt[e] = ld1(srw, (size_t)o * 4096 + ci * 16 + tap, f32);
}

// ---------------------------------------------------------------------------
// Shared tiled GEMM, 64x64 tile, BK=16, 256 threads, 4x4/thread, fp32 acc.
// MODE 0: q-proj -> g_qh/g_ql (bf16 hi/lo, *SCALE, [bh][n][32])
// MODE 1: conv split-K -> g_convp[z]
// MODE 2: kv -> g_kh/g_kl ([bh][key][32]) and g_vth/g_vtl ([bh][d][key])
// MODE 3: proj -> out (+proj_b, dtype-matched)
// ---------------------------------------------------------------------------
template <int MODE>
__launch_bounds__(256, 2)
__global__ void k_gemm(const void* __restrict__ Ax,
                       const void* __restrict__ Bp,
                       const void* __restrict__ biasp,
                       void* __restrict__ outp) {
  constexpr int LDB = (MODE == 2) ? 512 : 256;
  const int f32 = g_isf32;

  __shared__ float As[16][64];
  __shared__ float Bs[16][64];

  const int tid = threadIdx.x;
  const int tx = tid & 15, ty = tid >> 4;
  const int m0 = blockIdx.x * 64, n0 = blockIdx.y * 64;
  const int kbeg = (MODE == 1) ? blockIdx.z * 256 : 0;

  const int arow = tid >> 2;
  const int akk  = (tid & 3) * 4;
  const int bkk  = tid >> 4;
  const int bcc  = (tid & 15) * 4;

  float acc[4][4] = {};

  for (int k0 = kbeg; k0 < kbeg + 256; k0 += 16) {
    float4 av;
    if constexpr (MODE == 1) {
      int m = m0 + arow;
      int bb = m >> 8, sp = m & 255;
      int oh = sp >> 4, ow = sp & 15;
      int tap = k0 >> 8;
      int kh = tap >> 2, kw = tap & 3;
      int n = (4 * oh + kh) * 64 + 4 * ow + kw;
      int ci = (k0 & 255) + akk;
      av = ld4(Ax, ((size_t)(bb * 4096 + n) * 256) + ci, f32);
    } else if constexpr (MODE == 0) {
      av = ld4(Ax, (size_t)(m0 + arow) * 256 + k0 + akk, f32);
    } else {
      const float* A = (MODE == 2) ? g_ln : g_attn;
      av = *(const float4*)&A[(size_t)(m0 + arow) * 256 + k0 + akk];
    }
    As[akk + 0][arow] = av.x;
    As[akk + 1][arow] = av.y;
    As[akk + 2][arow] = av.z;
    As[akk + 3][arow] = av.w;

    float4 bv;
    if constexpr (MODE == 1)
      bv = *(const float4*)&g_wt[(size_t)(k0 + bkk) * 256 + n0 + bcc];
    else
      bv = ld4(Bp, (size_t)((k0 - kbeg) + bkk) * LDB + n0 + bcc, f32);
    *(float4*)&Bs[bkk][bcc] = bv;

    __syncthreads();
#pragma unroll
    for (int k = 0; k < 16; ++k) {
      float4 a = *(const float4*)&As[k][ty * 4];
      float4 b = *(const float4*)&Bs[k][tx * 4];
      float va[4] = {a.x, a.y, a.z, a.w};
      float vb[4] = {b.x, b.y, b.z, b.w};
#pragma unroll
      for (int i = 0; i < 4; ++i)
#pragma unroll
        for (int j = 0; j < 4; ++j)
          acc[i][j] = fmaf(va[i], vb[j], acc[i][j]);
    }
    __syncthreads();
  }

#pragma unroll
  for (int i = 0; i < 4; ++i) {
    int m = m0 + ty * 4 + i;
#pragma unroll
    for (int j = 0; j < 4; ++j) {
      int c = n0 + tx * 4 + j;
      float v = acc[i][j];
      if constexpr (MODE == 0) {
        int b = m >> 12, n = m & 4095;
        int h = c >> 5, d = c & 31;
        float vs = v * SCALE;
        unsigned short hi = f2bf(vs);
        unsigned short lo = f2bf(vs - bfbits2f(hi));
        size_t idx = (((size_t)(b * 8 + h) * 4096 + n) << 5) + d;
        g_qh[idx] = hi;
        g_ql[idx] = lo;
      } else if constexpr (MODE == 1) {
        g_convp[((size_t)blockIdx.z * 2048 + m) * 256 + c] = v;
      } else if constexpr (MODE == 2) {
        int s = c >> 8, h = (c >> 5) & 7, d = c & 31;
        int bb = m >> 8, nk = m & 255;
        unsigned short hi = f2bf(v);
        unsigned short lo = f2bf(v - bfbits2f(hi));
        if (s == 0) {
          size_t idx = (((size_t)(bb * 8 + h) * 256 + nk) << 5) + d;
          g_kh[idx] = hi; g_kl[idx] = lo;
        } else {
          size_t idx = (((size_t)(bb * 8 + h) * 32 + d) << 8) + nk;
          g_vth[idx] = hi; g_vtl[idx] = lo;
        }
      } else {
        float r = v + ld1(biasp, c, f32);
        if (f32) ((float*)outp)[(size_t)m * 256 + c] = r;
        else     ((unsigned short*)outp)[(size_t)m * 256 + c] = f2bf(r);
      }
    }
  }
}

// ---------------------------------------------------------------------------
__global__ void k_red(const void* __restrict__ biasp) {
  const int f32 = g_isf32;
  int row = blockIdx.x, c = threadIdx.x;
  size_t idx = (size_t)row * 256 + c;
  float s = 0.f;
#pragma unroll
  for (int z = 0; z < 16; ++z) s += g_convp[(size_t)z * (2048 * 256) + idx];
  g_conv[idx] = s + ld1(biasp, c, f32);
}

// ---------------------------------------------------------------------------
__global__ void k_ln(const void* __restrict__ lw, const void* __restrict__ lb) {
  const int f32 = g_isf32;
  int row = blockIdx.x;
  int t = threadIdx.x;
  float v = g_conv[(size_t)row * 256 + t];
  float s = v, sq = v * v;
#pragma unroll
  for (int off = 32; off >= 1; off >>= 1) {
    s += __shfl_down(s, off, 64);
    sq += __shfl_down(sq, off, 64);
  }
  __shared__ float rs[4], rq[4];
  int wid = t >> 6;
  if ((t & 63) == 0) { rs[wid] = s; rq[wid] = sq; }
  __syncthreads();
  float st = rs[0] + rs[1] + rs[2] + rs[3];
  float qt = rq[0] + rq[1] + rq[2] + rq[3];
  float mu = st * (1.0f / 256.0f);
  float var = qt * (1.0f / 256.0f) - mu * mu;
  float r = rsqrtf(var + 1e-5f);
  g_ln[(size_t)row * 256 + t] = (v - mu) * r * ld1(lw, t, f32) + ld1(lb, t, f32);
}

// ---------------------------------------------------------------------------
// MFMA attention. grid (64 n-blocks, 64 bh), 256 thr (4 waves × 16 q-rows).
// S = QK^T bf16x3 mfma; full softmax (Nk=256 in regs); P bf16 -> LDS;
// PV mfma with V hi/lo. K [256][40] + V_T [32][264] staged in LDS; P aliases
// the dead K region after the barrier.  74.75 KB LDS -> 2 blocks/CU.
// ---------------------------------------------------------------------------
__launch_bounds__(256, 2)
__global__ void k_attn() {
  __shared__ short smem[37376];
  short* skh = smem;              // K hi [256][40]   (pad: 2-way only, free)
  short* skl = smem + 10240;      // K lo [256][40]
  short* svh = smem + 20480;      // V_T hi [32][264] (pad: 2-way only, free)
  short* svl = smem + 28928;      // V_T lo [32][264]

  const int tid = threadIdx.x;
  const int bh = blockIdx.y;
  const int b = bh >> 3, h = bh & 7;

  // ---- stage K (hi/lo) ----
  {
    const uint4* gh = (const uint4*)(g_kh + (size_t)bh * 8192);
    const uint4* gl = (const uint4*)(g_kl + (size_t)bh * 8192);
    for (int i = tid; i < 1024; i += 256) {
      int key = i >> 2, part = i & 3;
      *(uint4*)&skh[key * 40 + part * 8] = gh[i];
      *(uint4*)&skl[key * 40 + part * 8] = gl[i];
    }
  }
  // ---- stage V_T (hi/lo) ----
  {
    const uint4* gh = (const uint4*)(g_vth + (size_t)bh * 8192);
    const uint4* gl = (const uint4*)(g_vtl + (size_t)bh * 8192);
    for (int i = tid; i < 1024; i += 256) {
      int d = i >> 5, off = (i & 31) * 8;
      *(uint4*)&svh[d * 264 + off] = gh[i];
      *(uint4*)&svl[d * 264 + off] = gl[i];
    }
  }
  __syncthreads();

  const int wave = tid >> 6, lane = tid & 63;
  const int quad = lane >> 4, l15 = lane & 15;
  const int n0 = blockIdx.x * 64 + wave * 16;

  // ---- Q fragments (A-layout: row=l15, k=quad*8+j) ----
  size_t qoff = ((size_t)bh * 4096 + n0 + l15) * 32 + quad * 8;
  bf16x8 qh = *(const bf16x8*)(g_qh + qoff);
  bf16x8 ql = *(const bf16x8*)(g_ql + qoff);

  // ---- S = Q K^T  (bf16x3) ----
  f32x4 sacc[16];
#pragma unroll
  for (int t = 0; t < 16; ++t) {
    bf16x8 kh = *(const bf16x8*)&skh[(t * 16 + l15) * 40 + quad * 8];
    bf16x8 kl = *(const bf16x8*)&skl[(t * 16 + l15) * 40 + quad * 8];
    f32x4 c = {0.f, 0.f, 0.f, 0.f};
    c = __builtin_amdgcn_mfma_f32_16x16x32_bf16(qh, kh, c, 0, 0, 0);
    c = __builtin_amdgcn_mfma_f32_16x16x32_bf16(ql, kh, c, 0, 0, 0);
    c = __builtin_amdgcn_mfma_f32_16x16x32_bf16(qh, kl, c, 0, 0, 0);
    sacc[t] = c;
  }

  // ---- row max (over 16 tiles in-lane, then 16-lane butterfly) ----
  float mrow[4];
#pragma unroll
  for (int r = 0; r < 4; ++r) {
    float m = sacc[0][r];
#pragma unroll
    for (int t = 1; t < 16; ++t) m = fmaxf(m, sacc[t][r]);
#pragma unroll
    for (int sft = 1; sft < 16; sft <<= 1)
      m = fmaxf(m, __shfl_xor(m, sft, 64));
    mrow[r] = m;
  }

  __syncthreads();   // all waves done reading K -> safe to alias P over K

  // ---- P = exp(S - m) -> bf16 -> LDS; l from the rounded P ----
  short* pw = smem + wave * 4224;   // P [16][264] per wave, aliases K region
  float lsum[4] = {0.f, 0.f, 0.f, 0.f};
#pragma unroll
  for (int t = 0; t < 16; ++t) {
#pragma unroll
    for (int r = 0; r < 4; ++r) {
      float p = __expf(sacc[t][r] - mrow[r]);
      unsigned short pb = f2bf(p);
      lsum[r] += bfbits2f(pb);
      pw[(quad * 4 + r) * 264 + t * 16 + l15] = (short)pb;
    }
  }
  float inv[4];
#pragma unroll
  for (int r = 0; r < 4; ++r) {
    float s = lsum[r];
#pragma unroll
    for (int sft = 1; sft < 16; sft <<= 1)
      s += __shfl_xor(s, sft, 64);
    inv[r] = 1.0f / s;
  }

  // ---- O = P V  (V hi/lo) ----
  f32x4 o0 = {0.f, 0.f, 0.f, 0.f}, o1 = {0.f, 0.f, 0.f, 0.f};
#pragma unroll
  for (int c = 0; c < 8; ++c) {
    bf16x8 pa = *(const bf16x8*)&pw[l15 * 264 + c * 32 + quad * 8];
    bf16x8 b0h = *(const bf16x8*)&svh[l15 * 264 + c * 32 + quad * 8];
    bf16x8 b0l = *(const bf16x8*)&svl[l15 * 264 + c * 32 + quad * 8];
    bf16x8 b1h = *(const bf16x8*)&svh[(16 + l15) * 264 + c * 32 + quad * 8];
    bf16x8 b1l = *(const bf16x8*)&svl[(16 + l15) * 264 + c * 32 + quad * 8];
    o0 = __builtin_amdgcn_mfma_f32_16x16x32_bf16(pa, b0h, o0, 0, 0, 0);
    o0 = __builtin_amdgcn_mfma_f32_16x16x32_bf16(pa, b0l, o0, 0, 0, 0);
    o1 = __builtin_amdgcn_mfma_f32_16x16x32_bf16(pa, b1h, o1, 0, 0, 0);
    o1 = __builtin_amdgcn_mfma_f32_16x16x32_bf16(pa, b1l, o1, 0, 0, 0);
  }

  // ---- normalize + store (C-layout: row=quad*4+r, col=l15 (+16)) ----
#pragma unroll
  for (int r = 0; r < 4; ++r) {
    int n = n0 + quad * 4 + r;
    size_t base = ((size_t)(b * 4096 + n)) * 256 + h * 32;
    g_attn[base + l15]      = o0[r] * inv[r];
    g_attn[base + 16 + l15] = o1[r] * inv[r];
  }
}

// ---------------------------------------------------------------------------
extern "C" void kernel_launch(void* const* d_in, const int* in_sizes, int n_in,
                              void* d_out, int out_size, void* d_ws, size_t ws_size,
                              hipStream_t stream) {
  const void* x   = d_in[0];
  const void* qw  = d_in[3];
  const void* kvw = d_in[4];
  const void* srw = d_in[5];
  const void* srb = d_in[6];
  const void* lnw = d_in[7];
  const void* lnb = d_in[8];
  const void* pw  = d_in[9];
  const void* pb  = d_in[10];

  k_detect<<<1, 256, 0, stream>>>(x);
  k_wt<<<4096, 256, 0, stream>>>(srw);
  // q projection -> bf16 hi/lo fragments (scaled, [bh][n][32])
  k_gemm<0><<<dim3(512, 4), 256, 0, stream>>>(x, qw, nullptr, nullptr);
  // conv as GEMM, split-K 16
  k_gemm<1><<<dim3(32, 4, 16), 256, 0, stream>>>(x, nullptr, nullptr, nullptr);
  k_red<<<2048, 256, 0, stream>>>(srb);
  k_ln<<<2048, 256, 0, stream>>>(lnw, lnb);
  // kv projection -> K hi/lo + V_T hi/lo
  k_gemm<2><<<dim3(32, 8), 256, 0, stream>>>(nullptr, kvw, nullptr, nullptr);
  // MFMA attention
  k_attn<<<dim3(64, 64), 256, 0, stream>>>();
  // output projection
  k_gemm<3><<<dim3(512, 4), 256, 0, stream>>>(nullptr, pw, pb, d_out);
}

// Round 6
// 311.411 us; speedup vs baseline: 2.3567x; 1.3587x over previous
//
#include <hip/hip_runtime.h>
#include <hip/hip_bf16.h>
#include <math.h>

#define DI __device__ __forceinline__

static constexpr float SCALE = 0.17677669529663687f;  // 1/sqrt(32)

typedef short bf16x8 __attribute__((ext_vector_type(8)));
typedef float f32x4 __attribute__((ext_vector_type(4)));

// ----------------------------- device scratch ------------------------------
__device__ int   g_isf32;                                // 0 = bf16 inputs, 1 = f32
__device__ unsigned short g_xh[(size_t)32768 * 256];     // x hi bf16
__device__ unsigned short g_xl[(size_t)32768 * 256];     // x lo bf16
__device__ unsigned short g_qwh[256 * 256],  g_qwl[256 * 256];    // qw^T * SCALE, [o][c]
__device__ unsigned short g_kvwh[512 * 256], g_kvwl[512 * 256];   // kvw^T, [o2][c]
__device__ unsigned short g_pwh[256 * 256],  g_pwl[256 * 256];    // pw^T, [o][c]
__device__ unsigned short g_wth[(size_t)256 * 4096];     // conv w^T, [o][tap*256+ci]
__device__ unsigned short g_wtl[(size_t)256 * 4096];
__device__ unsigned short g_qh[(size_t)64 * 4096 * 32];  // q hi, [bh][n][32]
__device__ unsigned short g_ql[(size_t)64 * 4096 * 32];
__device__ unsigned short g_kh[(size_t)64 * 256 * 32];   // K hi, [bh][key][32]
__device__ unsigned short g_kl[(size_t)64 * 256 * 32];
__device__ unsigned short g_vth[(size_t)64 * 32 * 256];  // V^T hi, [bh][d][key]
__device__ unsigned short g_vtl[(size_t)64 * 32 * 256];
__device__ float g_convp[(size_t)8 * 2048 * 256];        // conv split-K partials
__device__ float g_conv[(size_t)2048 * 256];             // conv out f32
__device__ unsigned short g_lnh[2048 * 256], g_lnl[2048 * 256];   // LN out hi/lo
__device__ unsigned short g_attnb[(size_t)32768 * 256];  // attn out bf16, [b*n][C]

DI float bfbits2f(unsigned short b) { return __uint_as_float(((unsigned)b) << 16); }

DI unsigned short f2bf(float f) {
  unsigned u = __float_as_uint(f);
  unsigned r = (u + 0x7fffu + ((u >> 16) & 1u)) >> 16;
  return (unsigned short)r;
}

DI float4 ld_bf4(const unsigned short* p) {
  ushort4 u = *(const ushort4*)p;
  return make_float4(bfbits2f(u.x), bfbits2f(u.y), bfbits2f(u.z), bfbits2f(u.w));
}

DI float ld1(const void* p, size_t i, int f32) {
  return f32 ? ((const float*)p)[i] : bfbits2f(((const unsigned short*)p)[i]);
}

DI float4 ld4(const void* p, size_t i, int f32) {
  if (f32) return *(const float4*)((const float*)p + i);
  return ld_bf4((const unsigned short*)p + i);
}

// ---------------------------------------------------------------------------
__global__ void k_detect(const void* __restrict__ xp) {
  __shared__ float red[256];
  int t = threadIdx.x;
  const unsigned short* p = (const unsigned short*)xp;
  float m = 0.f;
  for (int i = t; i < 16384; i += 256) {
    float v = fabsf(bfbits2f(p[i]));
    m = (v == v && v < 1e30f) ? fmaxf(m, v) : 1e30f;
  }
  red[t] = m;
  __syncthreads();
  for (int s = 128; s > 0; s >>= 1) {
    if (t < s) red[t] = fmaxf(red[t], red[t + s]);
    __syncthreads();
  }
  if (t == 0) g_isf32 = (red[0] > 1e4f) ? 1 : 0;
}

// ---------------------------------------------------------------------------
// x -> bf16 hi/lo
// ---------------------------------------------------------------------------
__global__ void k_cvt_x(const void* __restrict__ xp) {
  const int f32 = g_isf32;
  size_t i = ((size_t)blockIdx.x * 256 + threadIdx.x) * 4;
  float4 v = ld4(xp, i, f32);
  ushort4 h, l;
  h.x = f2bf(v.x); l.x = f2bf(v.x - bfbits2f(h.x));
  h.y = f2bf(v.y); l.y = f2bf(v.y - bfbits2f(h.y));
  h.z = f2bf(v.z); l.z = f2bf(v.z - bfbits2f(h.z));
  h.w = f2bf(v.w); l.w = f2bf(v.w - bfbits2f(h.w));
  *(ushort4*)&g_xh[i] = h;
  *(ushort4*)&g_xl[i] = l;
}

// ---------------------------------------------------------------------------
// qw/kvw/pw -> transposed hi/lo ([out][in]); SCALE folded into qw
// ---------------------------------------------------------------------------
__global__ void k_cvt_w(const void* __restrict__ qw, const void* __restrict__ kvw,
                        const void* __restrict__ pwp) {
  const int f32 = g_isf32;
  int e = blockIdx.x * 256 + threadIdx.x;   // over 262144
  float v;
  unsigned short *dh, *dl;
  size_t di;
  if (e < 65536) {
    int o = e >> 8, c = e & 255;
    v = ld1(qw, (size_t)c * 256 + o, f32) * SCALE;
    dh = g_qwh; dl = g_qwl; di = e;
  } else if (e < 196608) {
    int e2 = e - 65536;
    int o = e2 >> 8, c = e2 & 255;
    v = ld1(kvw, (size_t)c * 512 + o, f32);
    dh = g_kvwh; dl = g_kvwl; di = e2;
  } else {
    int e2 = e - 196608;
    int o = e2 >> 8, c = e2 & 255;
    v = ld1(pwp, (size_t)c * 256 + o, f32);
    dh = g_pwh; dl = g_pwl; di = e2;
  }
  unsigned short hi = f2bf(v);
  dh[di] = hi;
  dl[di] = f2bf(v - bfbits2f(hi));
}

// ---------------------------------------------------------------------------
// sr_w OIHW -> w^T [o][tap*256+ci] hi/lo
// ---------------------------------------------------------------------------
__global__ void k_wt(const void* __restrict__ srw) {
  const int f32 = g_isf32;
  int e = blockIdx.x * 256 + threadIdx.x;   // over 1048576
  int o = e >> 12, kk = e & 4095;
  int tap = kk >> 8, ci = kk & 255;
  float v = ld1(srw, (size_t)o * 4096 + ci * 16 + tap, f32);
  unsigned short hi = f2bf(v);
  g_wth[e] = hi;
  g_wtl[e] = f2bf(v - bfbits2f(hi));
}

// ---------------------------------------------------------------------------
// MFMA GEMM: block tile 64(M) x 256(N), BK=32, 256 thr (4 waves x 4m x 4n tiles).
// Operand layout: a-frag = A[row=lane&15][k=quad*8+j], b-frag = B^T[row][k];
// C: m = quad*4+reg (A rows), n = lane&15 (B rows).  bf16x3 (x2 for MODE 3).
// MODE 0: A=xh/xl,      B=qwT  -> g_qh/g_ql permuted [bh][n][32]
// MODE 1: A=x gathered, B=wtT  -> g_convp[z] f32 (split-K z=8, 512 k each)
// MODE 2: A=lnh/lnl,    B=kvwT -> g_kh/g_kl + g_vth/g_vtl (nblk: 0=K, 1=V)
// MODE 3: A=attnb (x1), B=pwT  -> out + bias (dtype-matched)
// ---------------------------------------------------------------------------
template <int MODE>
__launch_bounds__(256, 2)
__global__ void k_mgemm(const void* __restrict__ biasp, void* __restrict__ outp) {
  constexpr bool AH = (MODE != 3);            // A has lo part
  constexpr int KITERS = (MODE == 1) ? 16 : 8;
  constexpr int BKROW = (MODE == 1) ? 4096 : 256;

  __shared__ __align__(16) short sa_h[64 * 40];
  __shared__ __align__(16) short sa_l[64 * 40];
  __shared__ __align__(16) short sb_h[256 * 40];
  __shared__ __align__(16) short sb_l[256 * 40];

  const int tid = threadIdx.x;
  const int m0 = blockIdx.x * 64;
  const int nblk = (MODE == 2) ? blockIdx.y : 0;
  const int kz = (MODE == 1) ? blockIdx.z * 512 : 0;
  const int wave = tid >> 6, lane = tid & 63;
  const int quad = lane >> 4, l15 = lane & 15;

  f32x4 acc[4][4] = {};

  for (int it = 0; it < KITERS; ++it) {
    const int kb = kz + it * 32;
    // ---- stage A: 64 rows x 32 k ----
    {
      int row = tid >> 2, chunk = tid & 3;
      size_t src;
      if constexpr (MODE == 1) {
        int m = m0 + row;
        int bb = m >> 8, sp = m & 255;
        int oh = sp >> 4, ow = sp & 15;
        int tap = kb >> 8, kh = tap >> 2, kw = tap & 3;
        int n = (4 * oh + kh) * 64 + 4 * ow + kw;
        src = (((size_t)(bb * 4096 + n)) << 8) + (kb & 255) + chunk * 8;
      } else {
        src = (((size_t)(m0 + row)) << 8) + kb + chunk * 8;
      }
      const unsigned short* Ah =
          (MODE == 0 || MODE == 1) ? g_xh : (MODE == 2 ? g_lnh : g_attnb);
      *(uint4*)&sa_h[row * 40 + chunk * 8] = *(const uint4*)&Ah[src];
      if constexpr (AH) {
        const unsigned short* Al = (MODE == 0 || MODE == 1) ? g_xl : g_lnl;
        *(uint4*)&sa_l[row * 40 + chunk * 8] = *(const uint4*)&Al[src];
      }
    }
    // ---- stage B: 256 rows x 32 k ----
    {
      const unsigned short* Bh = (MODE == 0) ? g_qwh : (MODE == 1) ? g_wth
                               : (MODE == 2) ? g_kvwh : g_pwh;
      const unsigned short* Bl = (MODE == 0) ? g_qwl : (MODE == 1) ? g_wtl
                               : (MODE == 2) ? g_kvwl : g_pwl;
#pragma unroll
      for (int i = 0; i < 4; ++i) {
        int linear = tid + 256 * i;
        int row = linear >> 2, chunk = linear & 3;
        size_t src = (size_t)(nblk * 256 + row) * BKROW + kb + chunk * 8;
        *(uint4*)&sb_h[row * 40 + chunk * 8] = *(const uint4*)&Bh[src];
        *(uint4*)&sb_l[row * 40 + chunk * 8] = *(const uint4*)&Bl[src];
      }
    }
    __syncthreads();
    // ---- mfma ----
#pragma unroll
    for (int mt = 0; mt < 4; ++mt) {
      bf16x8 a_h = *(const bf16x8*)&sa_h[(mt * 16 + l15) * 40 + quad * 8];
      bf16x8 a_l;
      if constexpr (AH) a_l = *(const bf16x8*)&sa_l[(mt * 16 + l15) * 40 + quad * 8];
#pragma unroll
      for (int j = 0; j < 4; ++j) {
        int nrow = (4 * wave + j) * 16 + l15;
        bf16x8 b_h = *(const bf16x8*)&sb_h[nrow * 40 + quad * 8];
        bf16x8 b_l = *(const bf16x8*)&sb_l[nrow * 40 + quad * 8];
        f32x4 c = acc[mt][j];
        c = __builtin_amdgcn_mfma_f32_16x16x32_bf16(a_h, b_h, c, 0, 0, 0);
        if constexpr (AH)
          c = __builtin_amdgcn_mfma_f32_16x16x32_bf16(a_l, b_h, c, 0, 0, 0);
        c = __builtin_amdgcn_mfma_f32_16x16x32_bf16(a_h, b_l, c, 0, 0, 0);
        acc[mt][j] = c;
      }
    }
    __syncthreads();
  }

  // ---- epilogue ----
  const int f32 = g_isf32;
#pragma unroll
  for (int mt = 0; mt < 4; ++mt) {
#pragma unroll
    for (int j = 0; j < 4; ++j) {
#pragma unroll
      for (int r = 0; r < 4; ++r) {
        int m = m0 + mt * 16 + quad * 4 + r;
        int c = nblk * 256 + (4 * wave + j) * 16 + l15;
        float v = acc[mt][j][r];
        if constexpr (MODE == 0) {
          int b = m >> 12, n = m & 4095;
          int h = c >> 5, d = c & 31;
          unsigned short hi = f2bf(v);
          unsigned short lo = f2bf(v - bfbits2f(hi));
          size_t idx = (((size_t)(b * 8 + h) * 4096 + n) << 5) + d;
          g_qh[idx] = hi; g_ql[idx] = lo;
        } else if constexpr (MODE == 1) {
          g_convp[((size_t)blockIdx.z * 2048 + m) * 256 + c] = v;
        } else if constexpr (MODE == 2) {
          int s = c >> 8, h = (c >> 5) & 7, d = c & 31;
          int bb = m >> 8, nk = m & 255;
          unsigned short hi = f2bf(v);
          unsigned short lo = f2bf(v - bfbits2f(hi));
          if (s == 0) {
            size_t idx = (((size_t)(bb * 8 + h) * 256 + nk) << 5) + d;
            g_kh[idx] = hi; g_kl[idx] = lo;
          } else {
            size_t idx = (((size_t)(bb * 8 + h) * 32 + d) << 8) + nk;
            g_vth[idx] = hi; g_vtl[idx] = lo;
          }
        } else {
          float rr = v + ld1(biasp, c, f32);
          if (f32) ((float*)outp)[(size_t)m * 256 + c] = rr;
          else     ((unsigned short*)outp)[(size_t)m * 256 + c] = f2bf(rr);
        }
      }
    }
  }
}

// ---------------------------------------------------------------------------
__global__ void k_red(const void* __restrict__ biasp) {
  const int f32 = g_isf32;
  int row = blockIdx.x, c = threadIdx.x;
  size_t idx = (size_t)row * 256 + c;
  float s = 0.f;
#pragma unroll
  for (int z = 0; z < 8; ++z) s += g_convp[(size_t)z * (2048 * 256) + idx];
  g_conv[idx] = s + ld1(biasp, c, f32);
}

// ---------------------------------------------------------------------------
__global__ void k_ln(const void* __restrict__ lw, const void* __restrict__ lb) {
  const int f32 = g_isf32;
  int row = blockIdx.x;
  int t = threadIdx.x;
  float v = g_conv[(size_t)row * 256 + t];
  float s = v, sq = v * v;
#pragma unroll
  for (int off = 32; off >= 1; off >>= 1) {
    s += __shfl_down(s, off, 64);
    sq += __shfl_down(sq, off, 64);
  }
  __shared__ float rs[4], rq[4];
  int wid = t >> 6;
  if ((t & 63) == 0) { rs[wid] = s; rq[wid] = sq; }
  __syncthreads();
  float st = rs[0] + rs[1] + rs[2] + rs[3];
  float qt = rq[0] + rq[1] + rq[2] + rq[3];
  float mu = st * (1.0f / 256.0f);
  float var = qt * (1.0f / 256.0f) - mu * mu;
  float r = rsqrtf(var + 1e-5f);
  float o = (v - mu) * r * ld1(lw, t, f32) + ld1(lb, t, f32);
  unsigned short hi = f2bf(o);
  size_t idx = (size_t)row * 256 + t;
  g_lnh[idx] = hi;
  g_lnl[idx] = f2bf(o - bfbits2f(hi));
}

// ---------------------------------------------------------------------------
// MFMA attention (verified r5). Output now bf16 to g_attnb.
// ---------------------------------------------------------------------------
__launch_bounds__(256, 2)
__global__ void k_attn() {
  __shared__ short smem[37376];
  short* skh = smem;              // K hi [256][40]
  short* skl = smem + 10240;      // K lo
  short* svh = smem + 20480;      // V_T hi [32][264]
  short* svl = smem + 28928;      // V_T lo

  const int tid = threadIdx.x;
  const int bh = blockIdx.y;
  const int b = bh >> 3, h = bh & 7;

  {
    const uint4* gh = (const uint4*)(g_kh + (size_t)bh * 8192);
    const uint4* gl = (const uint4*)(g_kl + (size_t)bh * 8192);
    for (int i = tid; i < 1024; i += 256) {
      int key = i >> 2, part = i & 3;
      *(uint4*)&skh[key * 40 + part * 8] = gh[i];
      *(uint4*)&skl[key * 40 + part * 8] = gl[i];
    }
  }
  {
    const uint4* gh = (const uint4*)(g_vth + (size_t)bh * 8192);
    const uint4* gl = (const uint4*)(g_vtl + (size_t)bh * 8192);
    for (int i = tid; i < 1024; i += 256) {
      int d = i >> 5, off = (i & 31) * 8;
      *(uint4*)&svh[d * 264 + off] = gh[i];
      *(uint4*)&svl[d * 264 + off] = gl[i];
    }
  }
  __syncthreads();

  const int wave = tid >> 6, lane = tid & 63;
  const int quad = lane >> 4, l15 = lane & 15;
  const int n0 = blockIdx.x * 64 + wave * 16;

  size_t qoff = ((size_t)bh * 4096 + n0 + l15) * 32 + quad * 8;
  bf16x8 qh = *(const bf16x8*)(g_qh + qoff);
  bf16x8 ql = *(const bf16x8*)(g_ql + qoff);

  f32x4 sacc[16];
#pragma unroll
  for (int t = 0; t < 16; ++t) {
    bf16x8 kh = *(const bf16x8*)&skh[(t * 16 + l15) * 40 + quad * 8];
    bf16x8 kl = *(const bf16x8*)&skl[(t * 16 + l15) * 40 + quad * 8];
    f32x4 c = {0.f, 0.f, 0.f, 0.f};
    c = __builtin_amdgcn_mfma_f32_16x16x32_bf16(qh, kh, c, 0, 0, 0);
    c = __builtin_amdgcn_mfma_f32_16x16x32_bf16(ql, kh, c, 0, 0, 0);
    c = __builtin_amdgcn_mfma_f32_16x16x32_bf16(qh, kl, c, 0, 0, 0);
    sacc[t] = c;
  }

  float mrow[4];
#pragma unroll
  for (int r = 0; r < 4; ++r) {
    float m = sacc[0][r];
#pragma unroll
    for (int t = 1; t < 16; ++t) m = fmaxf(m, sacc[t][r]);
#pragma unroll
    for (int sft = 1; sft < 16; sft <<= 1)
      m = fmaxf(m, __shfl_xor(m, sft, 64));
    mrow[r] = m;
  }

  __syncthreads();

  short* pwv = smem + wave * 4224;
  float lsum[4] = {0.f, 0.f, 0.f, 0.f};
#pragma unroll
  for (int t = 0; t < 16; ++t) {
#pragma unroll
    for (int r = 0; r < 4; ++r) {
      float p = __expf(sacc[t][r] - mrow[r]);
      unsigned short pb = f2bf(p);
      lsum[r] += bfbits2f(pb);
      pwv[(quad * 4 + r) * 264 + t * 16 + l15] = (short)pb;
    }
  }
  float inv[4];
#pragma unroll
  for (int r = 0; r < 4; ++r) {
    float s = lsum[r];
#pragma unroll
    for (int sft = 1; sft < 16; sft <<= 1)
      s += __shfl_xor(s, sft, 64);
    inv[r] = 1.0f / s;
  }

  f32x4 o0 = {0.f, 0.f, 0.f, 0.f}, o1 = {0.f, 0.f, 0.f, 0.f};
#pragma unroll
  for (int c = 0; c < 8; ++c) {
    bf16x8 pa = *(const bf16x8*)&pwv[l15 * 264 + c * 32 + quad * 8];
    bf16x8 b0h = *(const bf16x8*)&svh[l15 * 264 + c * 32 + quad * 8];
    bf16x8 b0l = *(const bf16x8*)&svl[l15 * 264 + c * 32 + quad * 8];
    bf16x8 b1h = *(const bf16x8*)&svh[(16 + l15) * 264 + c * 32 + quad * 8];
    bf16x8 b1l = *(const bf16x8*)&svl[(16 + l15) * 264 + c * 32 + quad * 8];
    o0 = __builtin_amdgcn_mfma_f32_16x16x32_bf16(pa, b0h, o0, 0, 0, 0);
    o0 = __builtin_amdgcn_mfma_f32_16x16x32_bf16(pa, b0l, o0, 0, 0, 0);
    o1 = __builtin_amdgcn_mfma_f32_16x16x32_bf16(pa, b1h, o1, 0, 0, 0);
    o1 = __builtin_amdgcn_mfma_f32_16x16x32_bf16(pa, b1l, o1, 0, 0, 0);
  }

#pragma unroll
  for (int r = 0; r < 4; ++r) {
    int n = n0 + quad * 4 + r;
    unsigned short* op = g_attnb + ((size_t)(b * 4096 + n)) * 256 + h * 32;
    op[l15]      = f2bf(o0[r] * inv[r]);
    op[16 + l15] = f2bf(o1[r] * inv[r]);
  }
}

// ---------------------------------------------------------------------------
extern "C" void kernel_launch(void* const* d_in, const int* in_sizes, int n_in,
                              void* d_out, int out_size, void* d_ws, size_t ws_size,
                              hipStream_t stream) {
  const void* x   = d_in[0];
  const void* qw  = d_in[3];
  const void* kvw = d_in[4];
  const void* srw = d_in[5];
  const void* srb = d_in[6];
  const void* lnw = d_in[7];
  const void* lnb = d_in[8];
  const void* pw  = d_in[9];
  const void* pb  = d_in[10];

  k_detect<<<1, 256, 0, stream>>>(x);
  k_cvt_x<<<8192, 256, 0, stream>>>(x);
  k_cvt_w<<<1024, 256, 0, stream>>>(qw, kvw, pw);
  k_wt<<<4096, 256, 0, stream>>>(srw);
  // q projection (MFMA, scale folded into weights)
  k_mgemm<0><<<dim3(512, 1), 256, 0, stream>>>(nullptr, nullptr);
  // conv (MFMA, split-K z=8)
  k_mgemm<1><<<dim3(32, 1, 8), 256, 0, stream>>>(nullptr, nullptr);
  k_red<<<2048, 256, 0, stream>>>(srb);
  k_ln<<<2048, 256, 0, stream>>>(lnw, lnb);
  // kv projection (MFMA; nblk 0=K, 1=V)
  k_mgemm<2><<<dim3(32, 2), 256, 0, stream>>>(nullptr, nullptr);
  // attention (MFMA)
  k_attn<<<dim3(64, 64), 256, 0, stream>>>();
  // output projection (MFMA) + bias
  k_mgemm<3><<<dim3(512, 1), 256, 0, stream>>>(pb, d_out);
}

// Round 7
// 241.172 us; speedup vs baseline: 3.0430x; 1.2912x over previous
//
#include <hip/hip_runtime.h>
#include <hip/hip_bf16.h>
#include <math.h>

#define DI __device__ __forceinline__

static constexpr float SCALE = 0.17677669529663687f;  // 1/sqrt(32)

typedef short bf16x8 __attribute__((ext_vector_type(8)));
typedef float f32x4 __attribute__((ext_vector_type(4)));

// ----------------------------- device scratch ------------------------------
__device__ int   g_isf32;                                // 0 = bf16 inputs, 1 = f32
__device__ unsigned short g_qwh[256 * 256],  g_qwl[256 * 256];    // qw^T * SCALE, [o][c]
__device__ unsigned short g_kvwh[512 * 256], g_kvwl[512 * 256];   // kvw^T, [o2][c]
__device__ unsigned short g_pwh[256 * 256],  g_pwl[256 * 256];    // pw^T, [o][c]
__device__ unsigned short g_wth[(size_t)256 * 4096];     // conv w^T, [o][tap*256+ci]
__device__ unsigned short g_wtl[(size_t)256 * 4096];
__device__ unsigned short g_q[(size_t)64 * 4096 * 32];   // q bf16 (single), [bh][n][32]
__device__ unsigned short g_k[(size_t)64 * 256 * 32];    // K bf16, [bh][key][32]
__device__ unsigned short g_vt[(size_t)64 * 32 * 256];   // V^T bf16, [bh][d][key]
__device__ float g_convp[(size_t)16 * 2048 * 256];       // conv split-K partials
__device__ unsigned short g_lnh[2048 * 256], g_lnl[2048 * 256];   // LN out hi/lo
__device__ unsigned short g_attnb[(size_t)32768 * 256];  // attn out bf16, [b*n][C]

DI float bfbits2f(unsigned short b) { return __uint_as_float(((unsigned)b) << 16); }

DI unsigned short f2bf(float f) {
  unsigned u = __float_as_uint(f);
  unsigned r = (u + 0x7fffu + ((u >> 16) & 1u)) >> 16;
  return (unsigned short)r;
}

DI float4 ld_bf4(const unsigned short* p) {
  ushort4 u = *(const ushort4*)p;
  return make_float4(bfbits2f(u.x), bfbits2f(u.y), bfbits2f(u.z), bfbits2f(u.w));
}

DI float ld1(const void* p, size_t i, int f32) {
  return f32 ? ((const float*)p)[i] : bfbits2f(((const unsigned short*)p)[i]);
}

DI float4 ld4(const void* p, size_t i, int f32) {
  if (f32) return *(const float4*)((const float*)p + i);
  return ld_bf4((const unsigned short*)p + i);
}

// ---------------------------------------------------------------------------
__global__ void k_detect(const void* __restrict__ xp) {
  __shared__ float red[256];
  int t = threadIdx.x;
  const unsigned short* p = (const unsigned short*)xp;
  float m = 0.f;
  for (int i = t; i < 16384; i += 256) {
    float v = fabsf(bfbits2f(p[i]));
    m = (v == v && v < 1e30f) ? fmaxf(m, v) : 1e30f;
  }
  red[t] = m;
  __syncthreads();
  for (int s = 128; s > 0; s >>= 1) {
    if (t < s) red[t] = fmaxf(red[t], red[t + s]);
    __syncthreads();
  }
  if (t == 0) g_isf32 = (red[0] > 1e4f) ? 1 : 0;
}

// ---------------------------------------------------------------------------
// Weight prep (merged): blocks [0,1024): qw/kvw/pw -> transposed hi/lo;
// blocks [1024,5120): sr_w OIHW -> w^T [o][tap*256+ci] hi/lo.
// ---------------------------------------------------------------------------
__global__ void k_prep(const void* __restrict__ qw, const void* __restrict__ kvw,
                       const void* __restrict__ pwp, const void* __restrict__ srw) {
  const int f32 = g_isf32;
  int bid = blockIdx.x;
  if (bid < 1024) {
    int e = bid * 256 + threadIdx.x;   // over 262144
    float v;
    unsigned short *dh, *dl;
    size_t di;
    if (e < 65536) {
      int o = e >> 8, c = e & 255;
      v = ld1(qw, (size_t)c * 256 + o, f32) * SCALE;
      dh = g_qwh; dl = g_qwl; di = e;
    } else if (e < 196608) {
      int e2 = e - 65536;
      int o = e2 >> 8, c = e2 & 255;
      v = ld1(kvw, (size_t)c * 512 + o, f32);
      dh = g_kvwh; dl = g_kvwl; di = e2;
    } else {
      int e2 = e - 196608;
      int o = e2 >> 8, c = e2 & 255;
      v = ld1(pwp, (size_t)c * 256 + o, f32);
      dh = g_pwh; dl = g_pwl; di = e2;
    }
    unsigned short hi = f2bf(v);
    dh[di] = hi;
    dl[di] = f2bf(v - bfbits2f(hi));
  } else {
    int e = (bid - 1024) * 256 + threadIdx.x;   // over 1048576
    int o = e >> 12, kk = e & 4095;
    int tap = kk >> 8, ci = kk & 255;
    float v = ld1(srw, (size_t)o * 4096 + ci * 16 + tap, f32);
    unsigned short hi = f2bf(v);
    g_wth[e] = hi;
    g_wtl[e] = f2bf(v - bfbits2f(hi));
  }
}

// ---------------------------------------------------------------------------
// MFMA GEMM: block tile 64(M) x 256(N), BK=32, 256 thr (4 waves x 4m x 4n).
// A hi/lo split in-register during staging (modes 0/1 read x directly).
// MODE 0: A=x,          B=qwT  -> g_q bf16 single, [bh][n][32]
// MODE 1: A=x gathered, B=wtT  -> g_convp[z] f32 (split-K z=16, one tap each)
// MODE 2: A=lnh/lnl,    B=kvwT -> g_k + g_vt bf16 single (nblk: 0=K, 1=V)
// MODE 3: A=attnb (x1), B=pwT  -> out + bias (dtype-matched)
// ---------------------------------------------------------------------------
template <int MODE>
__launch_bounds__(256, 3)
__global__ void k_mgemm(const void* __restrict__ Ax,
                        const void* __restrict__ biasp, void* __restrict__ outp) {
  constexpr bool XIN = (MODE == 0 || MODE == 1);   // A comes from raw x input
  constexpr bool AH  = (MODE != 3);                // A has a lo part

  __shared__ __align__(16) short sa_h[64 * 40];
  __shared__ __align__(16) short sa_l[64 * 40];
  __shared__ __align__(16) short sb_h[256 * 40];
  __shared__ __align__(16) short sb_l[256 * 40];

  const int f32 = g_isf32;
  const int tid = threadIdx.x;
  const int m0 = blockIdx.x * 64;
  const int nblk = (MODE == 2) ? blockIdx.y : 0;
  const int kz = (MODE == 1) ? blockIdx.z * 256 : 0;
  const int wave = tid >> 6, lane = tid & 63;
  const int quad = lane >> 4, l15 = lane & 15;

  f32x4 acc[4][4] = {};

  for (int it = 0; it < 8; ++it) {
    const int kb = kz + it * 32;
    // ---- stage A: 64 rows x 32 k ----
    {
      int row = tid >> 2, chunk = tid & 3;
      size_t src;
      if constexpr (MODE == 1) {
        int m = m0 + row;
        int bb = m >> 8, sp = m & 255;
        int oh = sp >> 4, ow = sp & 15;
        int tap = kb >> 8, kh = tap >> 2, kw = tap & 3;
        int n = (4 * oh + kh) * 64 + 4 * ow + kw;
        src = (((size_t)(bb * 4096 + n)) << 8) + (kb & 255) + chunk * 8;
      } else {
        src = (((size_t)(m0 + row)) << 8) + kb + chunk * 8;
      }
      if constexpr (XIN) {
        float4 v0 = ld4(Ax, src, f32);
        float4 v1 = ld4(Ax, src + 4, f32);
        ushort4 h0, l0, h1, l1;
        h0.x = f2bf(v0.x); l0.x = f2bf(v0.x - bfbits2f(h0.x));
        h0.y = f2bf(v0.y); l0.y = f2bf(v0.y - bfbits2f(h0.y));
        h0.z = f2bf(v0.z); l0.z = f2bf(v0.z - bfbits2f(h0.z));
        h0.w = f2bf(v0.w); l0.w = f2bf(v0.w - bfbits2f(h0.w));
        h1.x = f2bf(v1.x); l1.x = f2bf(v1.x - bfbits2f(h1.x));
        h1.y = f2bf(v1.y); l1.y = f2bf(v1.y - bfbits2f(h1.y));
        h1.z = f2bf(v1.z); l1.z = f2bf(v1.z - bfbits2f(h1.z));
        h1.w = f2bf(v1.w); l1.w = f2bf(v1.w - bfbits2f(h1.w));
        *(ushort4*)&sa_h[row * 40 + chunk * 8]     = h0;
        *(ushort4*)&sa_h[row * 40 + chunk * 8 + 4] = h1;
        *(ushort4*)&sa_l[row * 40 + chunk * 8]     = l0;
        *(ushort4*)&sa_l[row * 40 + chunk * 8 + 4] = l1;
      } else if constexpr (MODE == 2) {
        *(uint4*)&sa_h[row * 40 + chunk * 8] = *(const uint4*)&g_lnh[src];
        *(uint4*)&sa_l[row * 40 + chunk * 8] = *(const uint4*)&g_lnl[src];
      } else {
        *(uint4*)&sa_h[row * 40 + chunk * 8] = *(const uint4*)&g_attnb[src];
      }
    }
    // ---- stage B: 256 rows x 32 k ----
    {
      constexpr int BKROW = (MODE == 1) ? 4096 : 256;
      const unsigned short* Bh = (MODE == 0) ? g_qwh : (MODE == 1) ? g_wth
                               : (MODE == 2) ? g_kvwh : g_pwh;
      const unsigned short* Bl = (MODE == 0) ? g_qwl : (MODE == 1) ? g_wtl
                               : (MODE == 2) ? g_kvwl : g_pwl;
#pragma unroll
      for (int i = 0; i < 4; ++i) {
        int linear = tid + 256 * i;
        int row = linear >> 2, chunk = linear & 3;
        size_t src = (size_t)(nblk * 256 + row) * BKROW + kb + chunk * 8;
        *(uint4*)&sb_h[row * 40 + chunk * 8] = *(const uint4*)&Bh[src];
        *(uint4*)&sb_l[row * 40 + chunk * 8] = *(const uint4*)&Bl[src];
      }
    }
    __syncthreads();
    // ---- mfma ----
#pragma unroll
    for (int mt = 0; mt < 4; ++mt) {
      bf16x8 a_h = *(const bf16x8*)&sa_h[(mt * 16 + l15) * 40 + quad * 8];
      bf16x8 a_l;
      if constexpr (AH) a_l = *(const bf16x8*)&sa_l[(mt * 16 + l15) * 40 + quad * 8];
#pragma unroll
      for (int j = 0; j < 4; ++j) {
        int nrow = (4 * wave + j) * 16 + l15;
        bf16x8 b_h = *(const bf16x8*)&sb_h[nrow * 40 + quad * 8];
        bf16x8 b_l = *(const bf16x8*)&sb_l[nrow * 40 + quad * 8];
        f32x4 c = acc[mt][j];
        c = __builtin_amdgcn_mfma_f32_16x16x32_bf16(a_h, b_h, c, 0, 0, 0);
        if constexpr (AH)
          c = __builtin_amdgcn_mfma_f32_16x16x32_bf16(a_l, b_h, c, 0, 0, 0);
        c = __builtin_amdgcn_mfma_f32_16x16x32_bf16(a_h, b_l, c, 0, 0, 0);
        acc[mt][j] = c;
      }
    }
    __syncthreads();
  }

  // ---- epilogue (C-layout: m = mt*16 + quad*4 + r, n = tile n + l15) ----
#pragma unroll
  for (int mt = 0; mt < 4; ++mt) {
#pragma unroll
    for (int j = 0; j < 4; ++j) {
#pragma unroll
      for (int r = 0; r < 4; ++r) {
        int m = m0 + mt * 16 + quad * 4 + r;
        int c = nblk * 256 + (4 * wave + j) * 16 + l15;
        float v = acc[mt][j][r];
        if constexpr (MODE == 0) {
          int b = m >> 12, n = m & 4095;
          int h = c >> 5, d = c & 31;
          g_q[(((size_t)(b * 8 + h) * 4096 + n) << 5) + d] = f2bf(v);
        } else if constexpr (MODE == 1) {
          g_convp[((size_t)blockIdx.z * 2048 + m) * 256 + c] = v;
        } else if constexpr (MODE == 2) {
          int s = c >> 8, h = (c >> 5) & 7, d = c & 31;
          int bb = m >> 8, nk = m & 255;
          if (s == 0)
            g_k[(((size_t)(bb * 8 + h) * 256 + nk) << 5) + d] = f2bf(v);
          else
            g_vt[(((size_t)(bb * 8 + h) * 32 + d) << 8) + nk] = f2bf(v);
        } else {
          float rr = v + ld1(biasp, c, f32);
          if (f32) ((float*)outp)[(size_t)m * 256 + c] = rr;
          else     ((unsigned short*)outp)[(size_t)m * 256 + c] = f2bf(rr);
        }
      }
    }
  }
}

// ---------------------------------------------------------------------------
// Fused split-K reduce + bias + LayerNorm -> lnh/lnl.  grid 2048, block 256.
// ---------------------------------------------------------------------------
__global__ void k_redln(const void* __restrict__ srb,
                        const void* __restrict__ lw, const void* __restrict__ lb) {
  const int f32 = g_isf32;
  int row = blockIdx.x, t = threadIdx.x;
  size_t idx = (size_t)row * 256 + t;
  float v = 0.f;
#pragma unroll
  for (int z = 0; z < 16; ++z) v += g_convp[(size_t)z * (2048 * 256) + idx];
  v += ld1(srb, t, f32);
  float s = v, sq = v * v;
#pragma unroll
  for (int off = 32; off >= 1; off >>= 1) {
    s += __shfl_down(s, off, 64);
    sq += __shfl_down(sq, off, 64);
  }
  __shared__ float rs[4], rq[4];
  int wid = t >> 6;
  if ((t & 63) == 0) { rs[wid] = s; rq[wid] = sq; }
  __syncthreads();
  float st = rs[0] + rs[1] + rs[2] + rs[3];
  float qt = rq[0] + rq[1] + rq[2] + rq[3];
  float mu = st * (1.0f / 256.0f);
  float var = qt * (1.0f / 256.0f) - mu * mu;
  float r = rsqrtf(var + 1e-5f);
  float o = (v - mu) * r * ld1(lw, t, f32) + ld1(lb, t, f32);
  unsigned short hi = f2bf(o);
  g_lnh[idx] = hi;
  g_lnl[idx] = f2bf(o - bfbits2f(hi));
}

// ---------------------------------------------------------------------------
// MFMA attention, S^T formulation, all-bf16 operands, no P LDS round-trip.
// grid (64 n-blocks, 64 bh), 4 waves x 16 q-rows.
//   S^T tile t: mfma(A=K[keys t*16+..][d], B=Q^T) -> lane holds
//     S[q=l15][key=t*16+quad*4+r]   (Q reg doubles as B-frag: same layout)
//   softmax stats: in-lane over (t,r), shfl_xor(16,32) over quads.
//   P^T b-frags built in-register: 8 shfl + 4 selects per 32-key chunk.
//   O^T = mfma(A=V^T, B=P^T) -> lane holds O^T[d=quad*4+r][q=l15].
// LDS: K [256][40] + V^T [32][264] = 37.4 KB.
// ---------------------------------------------------------------------------
__launch_bounds__(256, 3)
__global__ void k_attn() {
  __shared__ short smem[18688];
  short* sk  = smem;            // K [256][40]
  short* svt = smem + 10240;    // V^T [32][264]

  const int tid = threadIdx.x;
  const int bh = blockIdx.y;
  const int b = bh >> 3, h = bh & 7;

  {
    const uint4* gk = (const uint4*)(g_k + (size_t)bh * 8192);
    const uint4* gv = (const uint4*)(g_vt + (size_t)bh * 8192);
    for (int i = tid; i < 1024; i += 256) {
      int key = i >> 2, part = i & 3;
      *(uint4*)&sk[key * 40 + part * 8] = gk[i];
      int d = i >> 5, off = (i & 31) * 8;
      *(uint4*)&svt[d * 264 + off] = gv[i];
    }
  }
  __syncthreads();

  const int wave = tid >> 6, lane = tid & 63;
  const int quad = lane >> 4, l15 = lane & 15;
  const int n0 = blockIdx.x * 64 + wave * 16;

  // Q fragment: Q[q=l15][d=quad*8+j] — serves as B-frag of Q^T.
  bf16x8 qv = *(const bf16x8*)(g_q + ((size_t)bh * 4096 + n0 + l15) * 32 + quad * 8);

  // ---- S^T = K Q^T ----
  f32x4 sacc[16];
#pragma unroll
  for (int t = 0; t < 16; ++t) {
    bf16x8 kf = *(const bf16x8*)&sk[(t * 16 + l15) * 40 + quad * 8];
    f32x4 c = {0.f, 0.f, 0.f, 0.f};
    sacc[t] = __builtin_amdgcn_mfma_f32_16x16x32_bf16(kf, qv, c, 0, 0, 0);
  }

  // ---- row max over keys (in-lane + cross-quad) ----
  float m = sacc[0][0];
#pragma unroll
  for (int t = 0; t < 16; ++t) {
#pragma unroll
    for (int r = 0; r < 4; ++r) m = fmaxf(m, sacc[t][r]);
  }
  m = fmaxf(m, __shfl_xor(m, 16, 64));
  m = fmaxf(m, __shfl_xor(m, 32, 64));

  // ---- P = exp(S-m) -> bf16, packed pairs; l = sum of rounded P ----
  unsigned plo[16], phi[16];
  float ls = 0.f;
#pragma unroll
  for (int t = 0; t < 16; ++t) {
    unsigned short p0 = f2bf(__expf(sacc[t][0] - m));
    unsigned short p1 = f2bf(__expf(sacc[t][1] - m));
    unsigned short p2 = f2bf(__expf(sacc[t][2] - m));
    unsigned short p3 = f2bf(__expf(sacc[t][3] - m));
    ls += bfbits2f(p0) + bfbits2f(p1) + bfbits2f(p2) + bfbits2f(p3);
    plo[t] = (unsigned)p0 | ((unsigned)p1 << 16);
    phi[t] = (unsigned)p2 | ((unsigned)p3 << 16);
  }
  ls += __shfl_xor(ls, 16, 64);
  ls += __shfl_xor(ls, 32, 64);
  float inv = 1.0f / ls;

  // ---- O^T = V^T P^T ----
  f32x4 o0 = {0.f, 0.f, 0.f, 0.f}, o1 = {0.f, 0.f, 0.f, 0.f};
  const int laneA = ((quad & 1) << 5) + l15;
  const int laneB = laneA + 16;
  const bool hiT = quad >= 2;
#pragma unroll
  for (int c = 0; c < 8; ++c) {
    unsigned a0 = __shfl(plo[2 * c], laneA, 64), b0 = __shfl(plo[2 * c + 1], laneA, 64);
    unsigned a1 = __shfl(phi[2 * c], laneA, 64), b1 = __shfl(phi[2 * c + 1], laneA, 64);
    unsigned a2 = __shfl(plo[2 * c], laneB, 64), b2 = __shfl(plo[2 * c + 1], laneB, 64);
    unsigned a3 = __shfl(phi[2 * c], laneB, 64), b3 = __shfl(phi[2 * c + 1], laneB, 64);
    uint4 pk = make_uint4(hiT ? b0 : a0, hiT ? b1 : a1, hiT ? b2 : a2, hiT ? b3 : a3);
    bf16x8 pf = *(bf16x8*)&pk;
    bf16x8 v0 = *(const bf16x8*)&svt[l15 * 264 + c * 32 + quad * 8];
    bf16x8 v1 = *(const bf16x8*)&svt[(16 + l15) * 264 + c * 32 + quad * 8];
    o0 = __builtin_amdgcn_mfma_f32_16x16x32_bf16(v0, pf, o0, 0, 0, 0);
    o1 = __builtin_amdgcn_mfma_f32_16x16x32_bf16(v1, pf, o1, 0, 0, 0);
  }

  // ---- store: lane holds O^T[d=quad*4+r][q=l15] -> two 8B stores ----
  size_t base = ((size_t)(b * 4096 + n0 + l15)) * 256 + h * 32 + quad * 4;
  ushort4 u0, u1;
  u0.x = f2bf(o0[0] * inv); u0.y = f2bf(o0[1] * inv);
  u0.z = f2bf(o0[2] * inv); u0.w = f2bf(o0[3] * inv);
  u1.x = f2bf(o1[0] * inv); u1.y = f2bf(o1[1] * inv);
  u1.z = f2bf(o1[2] * inv); u1.w = f2bf(o1[3] * inv);
  *(ushort4*)&g_attnb[base]      = u0;
  *(ushort4*)&g_attnb[base + 16] = u1;
}

// ---------------------------------------------------------------------------
extern "C" void kernel_launch(void* const* d_in, const int* in_sizes, int n_in,
                              void* d_out, int out_size, void* d_ws, size_t ws_size,
                              hipStream_t stream) {
  const void* x   = d_in[0];
  const void* qw  = d_in[3];
  const void* kvw = d_in[4];
  const void* srw = d_in[5];
  const void* srb = d_in[6];
  const void* lnw = d_in[7];
  const void* lnb = d_in[8];
  const void* pw  = d_in[9];
  const void* pb  = d_in[10];

  k_detect<<<1, 256, 0, stream>>>(x);
  k_prep<<<5120, 256, 0, stream>>>(qw, kvw, pw, srw);
  // q projection (MFMA, scale folded) -> g_q single bf16
  k_mgemm<0><<<dim3(512, 1), 256, 0, stream>>>(x, nullptr, nullptr);
  // conv (MFMA, split-K z=16, one tap per z)
  k_mgemm<1><<<dim3(32, 1, 16), 256, 0, stream>>>(x, nullptr, nullptr);
  // fused reduce + bias + LN
  k_redln<<<2048, 256, 0, stream>>>(srb, lnw, lnb);
  // kv projection (MFMA) -> g_k / g_vt single bf16
  k_mgemm<2><<<dim3(32, 2), 256, 0, stream>>>(nullptr, nullptr, nullptr);
  // attention (MFMA, S^T formulation)
  k_attn<<<dim3(64, 64), 256, 0, stream>>>();
  // output projection (MFMA) + bias
  k_mgemm<3><<<dim3(512, 1), 256, 0, stream>>>(nullptr, pb, d_out);
}